// Round 1
// baseline (556.668 us; speedup 1.0000x reference)
//
#include <hip/hip_runtime.h>
#include <hip/hip_bf16.h>

#define NNODES 100000
#define NEDGES 3200000
#define DIN 512
#define DOUT 128

typedef __attribute__((ext_vector_type(8))) short bf16x8;   // 8 bf16 = 4 VGPRs
typedef __attribute__((ext_vector_type(4))) float f32x4;
typedef __attribute__((ext_vector_type(4))) unsigned short us4;

static __device__ __forceinline__ unsigned short f2bf(float f) {
  union { float f; unsigned u; } v; v.f = f;
  unsigned r = v.u + 0x7fffu + ((v.u >> 16) & 1u);
  return (unsigned short)(r >> 16);
}

// ---- W transpose + cast: Wt[n][k] bf16 from W[k][n] fp32 ----
__global__ void wt_kernel(const float* __restrict__ W, unsigned short* __restrict__ Wt) {
  int idx = blockIdx.x * blockDim.x + threadIdx.x;   // 65536 threads
  int k = idx >> 7, n = idx & 127;
  Wt[n * DIN + k] = f2bf(W[k * DOUT + n]);
}

// ---- row_ptr[r] = lower_bound(adj_rows, r), r in [0, N] ----
__global__ void rowptr_kernel(const int* __restrict__ rows, int* __restrict__ rp) {
  int r = blockIdx.x * blockDim.x + threadIdx.x;
  if (r > NNODES) return;
  int lo = 0, hi = NEDGES;
  while (lo < hi) { int mid = (lo + hi) >> 1; if (rows[mid] < r) lo = mid + 1; else hi = mid; }
  rp[r] = lo;
}

// ---- GEMM: h[M][128] = x[M][512] (fp32 -> bf16) @ W ----
#define BM 128
#define BK 64
#define LDA 72   // padded K stride (elems) to break bank alignment

__launch_bounds__(256, 2)
__global__ void gemm_kernel(const float* __restrict__ x, const unsigned short* __restrict__ Wt,
                            float* __restrict__ h) {
  __shared__ unsigned short Asb[BM][LDA];
  __shared__ unsigned short Bsb[DOUT][LDA];
  const int t = threadIdx.x;
  const int lane = t & 63;
  const int w = t >> 6;            // wave 0..3
  const int wm = w >> 1, wn = w & 1;
  const int m0 = blockIdx.x * BM;

  f32x4 acc[4][4] = {};

  const int rr = t >> 4;           // 0..15
  const int c4 = (t & 15) * 4;     // 0..60

  for (int kt = 0; kt < DIN; kt += BK) {
    // stage A tile (convert fp32 -> bf16), rows OOB -> 0
    #pragma unroll
    for (int it = 0; it < 8; ++it) {
      int row = it * 16 + rr;
      int gm = m0 + row;
      float4 v = make_float4(0.f, 0.f, 0.f, 0.f);
      if (gm < NNODES) v = *(const float4*)(x + (long)gm * DIN + kt + c4);
      us4 b; b.x = f2bf(v.x); b.y = f2bf(v.y); b.z = f2bf(v.z); b.w = f2bf(v.w);
      *(us4*)&Asb[row][c4] = b;
    }
    // stage B tile (already bf16, layout Wt[n][k])
    #pragma unroll
    for (int it = 0; it < 8; ++it) {
      int n = it * 16 + rr;
      us4 b = *(const us4*)(Wt + n * DIN + kt + c4);
      *(us4*)&Bsb[n][c4] = b;
    }
    __syncthreads();

    #pragma unroll
    for (int ks = 0; ks < 2; ++ks) {
      const int ko = ks * 32 + (lane >> 4) * 8;
      bf16x8 af[4], bfr[4];
      #pragma unroll
      for (int fm = 0; fm < 4; ++fm)
        af[fm] = *(const bf16x8*)&Asb[wm * 64 + fm * 16 + (lane & 15)][ko];
      #pragma unroll
      for (int fn = 0; fn < 4; ++fn)
        bfr[fn] = *(const bf16x8*)&Bsb[wn * 64 + fn * 16 + (lane & 15)][ko];
      #pragma unroll
      for (int fm = 0; fm < 4; ++fm)
        #pragma unroll
        for (int fn = 0; fn < 4; ++fn)
          acc[fm][fn] = __builtin_amdgcn_mfma_f32_16x16x32_bf16(af[fm], bfr[fn], acc[fm][fn], 0, 0, 0);
    }
    __syncthreads();
  }

  // epilogue: D lane mapping col = lane&15, row = (lane>>4)*4 + i  (m89-verified)
  const int col_in = lane & 15;
  const int rbase = (lane >> 4) * 4;
  #pragma unroll
  for (int fm = 0; fm < 4; ++fm) {
    #pragma unroll
    for (int i = 0; i < 4; ++i) {
      int gm = m0 + wm * 64 + fm * 16 + rbase + i;
      if (gm < NNODES) {
        float* dst = h + (long)gm * DOUT + wn * 64;
        #pragma unroll
        for (int fn = 0; fn < 4; ++fn)
          dst[fn * 16 + col_in] = acc[fm][fn][i];
      }
    }
  }
}

// ---- SpMM + relu: one wave per row, lane owns 2 cols ----
__global__ void spmm_kernel(const float* __restrict__ h, const int* __restrict__ cols,
                            const float* __restrict__ vals, const int* __restrict__ rp,
                            float* __restrict__ out) {
  int wid = blockIdx.x * 4 + (threadIdx.x >> 6);
  int lane = threadIdx.x & 63;
  if (wid >= NNODES) return;
  int s = __builtin_amdgcn_readfirstlane(rp[wid]);
  int e = __builtin_amdgcn_readfirstlane(rp[wid + 1]);
  float ax = 0.f, ay = 0.f;
  const float2* h2 = (const float2*)h;
  int i = s;
  for (; i + 2 <= e; i += 2) {
    int c0 = __builtin_amdgcn_readfirstlane(cols[i]);
    int c1 = __builtin_amdgcn_readfirstlane(cols[i + 1]);
    float v0 = vals[i], v1 = vals[i + 1];
    float2 g0 = h2[c0 * 64 + lane];
    float2 g1 = h2[c1 * 64 + lane];
    ax += v0 * g0.x; ay += v0 * g0.y;
    ax += v1 * g1.x; ay += v1 * g1.y;
  }
  if (i < e) {
    int c0 = __builtin_amdgcn_readfirstlane(cols[i]);
    float v0 = vals[i];
    float2 g0 = h2[c0 * 64 + lane];
    ax += v0 * g0.x; ay += v0 * g0.y;
  }
  float2 o; o.x = ax > 0.f ? ax : 0.f; o.y = ay > 0.f ? ay : 0.f;
  ((float2*)out)[(long)wid * 64 + lane] = o;
}

extern "C" void kernel_launch(void* const* d_in, const int* in_sizes, int n_in,
                              void* d_out, int out_size, void* d_ws, size_t ws_size,
                              hipStream_t stream) {
  const float* x        = (const float*)d_in[0];
  const float* W        = (const float*)d_in[1];
  const int*   adj_rows = (const int*)d_in[2];
  const int*   adj_cols = (const int*)d_in[3];
  const float* adj_vals = (const float*)d_in[4];
  float* out = (float*)d_out;

  char* ws = (char*)d_ws;
  float* h           = (float*)ws;                                  // 51,200,000 B
  unsigned short* Wt = (unsigned short*)(ws + 51200000);            // 131,072 B
  int* rp            = (int*)(ws + 51200000 + 131072);              // 400,004 B

  wt_kernel<<<256, 256, 0, stream>>>(W, Wt);
  rowptr_kernel<<<(NNODES + 1 + 255) / 256, 256, 0, stream>>>(adj_rows, rp);
  gemm_kernel<<<(NNODES + BM - 1) / BM, 256, 0, stream>>>(x, Wt, h);
  spmm_kernel<<<(NNODES + 3) / 4, 256, 0, stream>>>(h, adj_cols, adj_vals, rp, out);
}

// Round 4
// 457.022 us; speedup vs baseline: 1.2180x; 1.2180x over previous
//
#include <hip/hip_runtime.h>
#include <hip/hip_bf16.h>

#define NNODES 100000
#define NEDGES 3200000
#define DIN 512
#define DOUT 128

typedef __attribute__((ext_vector_type(8))) short bf16x8;   // 8 bf16 = 4 VGPRs
typedef __attribute__((ext_vector_type(4))) float f32x4;
typedef __attribute__((ext_vector_type(4))) unsigned short us4;

static __device__ __forceinline__ unsigned short f2bf(float f) {
  union { float f; unsigned u; } v; v.f = f;
  unsigned r = v.u + 0x7fffu + ((v.u >> 16) & 1u);
  return (unsigned short)(r >> 16);
}
static __device__ __forceinline__ float bflo(unsigned g) {
  union { unsigned u; float f; } v; v.u = g << 16; return v.f;
}
static __device__ __forceinline__ float bfhi(unsigned g) {
  union { unsigned u; float f; } v; v.u = g & 0xffff0000u; return v.f;
}

// ---- W transpose + cast: Wt[n][k] bf16 from W[k][n] fp32 (coalesced writes) ----
__global__ void wt_kernel(const float* __restrict__ W, unsigned short* __restrict__ Wt) {
  int idx = blockIdx.x * blockDim.x + threadIdx.x;   // 65536 threads
  int n = idx >> 9, k = idx & 511;                   // consecutive threads: k consecutive
  Wt[n * DIN + k] = f2bf(W[k * DOUT + n]);
}

// ---- row_ptr[r] = lower_bound(adj_rows, r), r in [0, N] ----
__global__ void rowptr_kernel(const int* __restrict__ rows, int* __restrict__ rp) {
  int r = blockIdx.x * blockDim.x + threadIdx.x;
  if (r > NNODES) return;
  int lo = 0, hi = NEDGES;
  while (lo < hi) { int mid = (lo + hi) >> 1; if (rows[mid] < r) lo = mid + 1; else hi = mid; }
  rp[r] = lo;
}

// ---- GEMM: h[M][128] (bf16) = x[M][512] (fp32 -> bf16) @ W ----
#define BM 128
#define BK 64
#define LDA 72   // padded K stride (elems), 144 B row pitch keeps 16B alignment

__launch_bounds__(256, 2)
__global__ void gemm_kernel(const float* __restrict__ x, const unsigned short* __restrict__ Wt,
                            unsigned short* __restrict__ h) {
  __shared__ unsigned short Asb[BM][LDA];
  __shared__ unsigned short Bsb[DOUT][LDA];
  const int t = threadIdx.x;
  const int lane = t & 63;
  const int w = t >> 6;            // wave 0..3
  const int wm = w >> 1, wn = w & 1;
  const int m0 = blockIdx.x * BM;

  f32x4 acc[4][4] = {};

  const int rr = t >> 4;           // 0..15
  const int c4 = (t & 15) * 4;     // 0..60

  for (int kt = 0; kt < DIN; kt += BK) {
    #pragma unroll
    for (int it = 0; it < 8; ++it) {
      int row = it * 16 + rr;
      int gm = m0 + row;
      float4 v = make_float4(0.f, 0.f, 0.f, 0.f);
      if (gm < NNODES) v = *(const float4*)(x + (long)gm * DIN + kt + c4);
      us4 b; b.x = f2bf(v.x); b.y = f2bf(v.y); b.z = f2bf(v.z); b.w = f2bf(v.w);
      *(us4*)&Asb[row][c4] = b;
    }
    #pragma unroll
    for (int it = 0; it < 8; ++it) {
      int n = it * 16 + rr;
      us4 b = *(const us4*)(Wt + n * DIN + kt + c4);
      *(us4*)&Bsb[n][c4] = b;
    }
    __syncthreads();

    #pragma unroll
    for (int ks = 0; ks < 2; ++ks) {
      const int ko = ks * 32 + (lane >> 4) * 8;
      bf16x8 af[4], bfr[4];
      #pragma unroll
      for (int fm = 0; fm < 4; ++fm)
        af[fm] = *(const bf16x8*)&Asb[wm * 64 + fm * 16 + (lane & 15)][ko];
      #pragma unroll
      for (int fn = 0; fn < 4; ++fn)
        bfr[fn] = *(const bf16x8*)&Bsb[wn * 64 + fn * 16 + (lane & 15)][ko];
      #pragma unroll
      for (int fm = 0; fm < 4; ++fm)
        #pragma unroll
        for (int fn = 0; fn < 4; ++fn)
          acc[fm][fn] = __builtin_amdgcn_mfma_f32_16x16x32_bf16(af[fm], bfr[fn], acc[fm][fn], 0, 0, 0);
    }
    __syncthreads();
  }

  // epilogue: D lane mapping col = lane&15, row = (lane>>4)*4 + i  (m89-verified)
  const int col_in = lane & 15;
  const int rbase = (lane >> 4) * 4;
  #pragma unroll
  for (int fm = 0; fm < 4; ++fm) {
    #pragma unroll
    for (int i = 0; i < 4; ++i) {
      int gm = m0 + wm * 64 + fm * 16 + rbase + i;
      if (gm < NNODES) {
        unsigned short* dst = h + (long)gm * DOUT + wn * 64;
        #pragma unroll
        for (int fn = 0; fn < 4; ++fn)
          dst[fn * 16 + col_in] = f2bf(acc[fm][fn][i]);
      }
    }
  }
}

// ---- SpMM + relu: one wave per row, lane owns 2 cols (bf16 pair per dword) ----
__global__ void spmm_kernel(const unsigned short* __restrict__ h, const int* __restrict__ cols,
                            const float* __restrict__ vals, const int* __restrict__ rp,
                            float* __restrict__ out) {
  int wid = blockIdx.x * 4 + (threadIdx.x >> 6);
  int lane = threadIdx.x & 63;
  if (wid >= NNODES) return;
  int s = __builtin_amdgcn_readfirstlane(rp[wid]);
  int e = __builtin_amdgcn_readfirstlane(rp[wid + 1]);
  float ax = 0.f, ay = 0.f;
  const unsigned* h2 = (const unsigned*)h;   // row stride = 64 dwords (128 bf16)
  int i = s;
  for (; i + 4 <= e; i += 4) {
    int c0 = __builtin_amdgcn_readfirstlane(cols[i]);
    int c1 = __builtin_amdgcn_readfirstlane(cols[i + 1]);
    int c2 = __builtin_amdgcn_readfirstlane(cols[i + 2]);
    int c3 = __builtin_amdgcn_readfirstlane(cols[i + 3]);
    float v0 = vals[i], v1 = vals[i + 1], v2 = vals[i + 2], v3 = vals[i + 3];
    unsigned g0 = h2[c0 * 64 + lane];
    unsigned g1 = h2[c1 * 64 + lane];
    unsigned g2 = h2[c2 * 64 + lane];
    unsigned g3 = h2[c3 * 64 + lane];
    ax += v0 * bflo(g0); ay += v0 * bfhi(g0);
    ax += v1 * bflo(g1); ay += v1 * bfhi(g1);
    ax += v2 * bflo(g2); ay += v2 * bfhi(g2);
    ax += v3 * bflo(g3); ay += v3 * bfhi(g3);
  }
  for (; i < e; ++i) {
    int c0 = __builtin_amdgcn_readfirstlane(cols[i]);
    float v0 = vals[i];
    unsigned g0 = h2[c0 * 64 + lane];
    ax += v0 * bflo(g0); ay += v0 * bfhi(g0);
  }
  float2 o; o.x = ax > 0.f ? ax : 0.f; o.y = ay > 0.f ? ay : 0.f;
  ((float2*)out)[(long)wid * 64 + lane] = o;
}

extern "C" void kernel_launch(void* const* d_in, const int* in_sizes, int n_in,
                              void* d_out, int out_size, void* d_ws, size_t ws_size,
                              hipStream_t stream) {
  const float* x        = (const float*)d_in[0];
  const float* W        = (const float*)d_in[1];
  const int*   adj_rows = (const int*)d_in[2];
  const int*   adj_cols = (const int*)d_in[3];
  const float* adj_vals = (const float*)d_in[4];
  float* out = (float*)d_out;

  char* ws = (char*)d_ws;
  unsigned short* h  = (unsigned short*)ws;                         // 25,600,000 B
  unsigned short* Wt = (unsigned short*)(ws + 25600000);            // 131,072 B
  int* rp            = (int*)(ws + 25600000 + 131072);              // 400,004 B

  wt_kernel<<<256, 256, 0, stream>>>(W, Wt);
  rowptr_kernel<<<(NNODES + 1 + 255) / 256, 256, 0, stream>>>(adj_rows, rp);
  gemm_kernel<<<(NNODES + BM - 1) / BM, 256, 0, stream>>>(x, Wt, h);
  spmm_kernel<<<(NNODES + 3) / 4, 256, 0, stream>>>(h, adj_cols, adj_vals, rp, out);
}